// Round 1
// baseline (307.487 us; speedup 1.0000x reference)
//
#include <hip/hip_runtime.h>

#define EPS 1e-10f

// One wave (64 lanes) per ray. N=128 samples/ray, lane handles samples 2L, 2L+1.
__global__ __launch_bounds__(256) void vr_kernel(
    const float* __restrict__ alpha,   // [R,128]
    const float* __restrict__ rgbs,    // [R,128,3]
    float* __restrict__ out,           // [R,3]
    int R)
{
    const int gtid = blockIdx.x * blockDim.x + threadIdx.x;
    const int ray  = gtid >> 6;
    const int lane = threadIdx.x & 63;
    if (ray >= R) return;

    const float* a = alpha + (size_t)ray * 128;
    const float* c = rgbs  + (size_t)ray * 384;

    // Coalesced: lane L loads alpha[2L], alpha[2L+1]
    const float2 av = *(const float2*)(a + 2 * lane);
    const float t0 = 1.0f - av.x + EPS;
    const float t1 = 1.0f - av.y + EPS;
    const float local = t0 * t1;

    // Inclusive scan (product) across 64 lanes
    float scan = local;
    #pragma unroll
    for (int off = 1; off < 64; off <<= 1) {
        float v = __shfl_up(scan, off, 64);
        if (lane >= off) scan *= v;
    }
    // Exclusive prefix: product of all lanes < lane (exact, no division)
    float excl = __shfl_up(scan, 1, 64);
    if (lane == 0) excl = 1.0f;

    // trans[2L] = excl, trans[2L+1] = excl * t0  (exclusive cumprod, shift=1)
    const float w0 = excl * av.x;
    const float w1 = excl * t0 * av.y;

    // Coalesced rgb loads: lane L owns 6 consecutive floats at offset 6L
    const float2* cp = (const float2*)(c + 6 * lane);
    const float2 p0 = cp[0];  // r0 g0
    const float2 p1 = cp[1];  // b0 r1
    const float2 p2 = cp[2];  // g1 b1

    float sr = w0 * p0.x + w1 * p1.y;
    float sg = w0 * p0.y + w1 * p2.x;
    float sb = w0 * p1.x + w1 * p2.y;

    // Wave reduction over 64 lanes
    #pragma unroll
    for (int off = 32; off > 0; off >>= 1) {
        sr += __shfl_down(sr, off, 64);
        sg += __shfl_down(sg, off, 64);
        sb += __shfl_down(sb, off, 64);
    }

    if (lane == 0) {
        float* o = out + (size_t)ray * 3;
        o[0] = sr;
        o[1] = sg;
        o[2] = sb;
    }
}

extern "C" void kernel_launch(void* const* d_in, const int* in_sizes, int n_in,
                              void* d_out, int out_size, void* d_ws, size_t ws_size,
                              hipStream_t stream) {
    const float* alpha = (const float*)d_in[0];
    const float* rgbs  = (const float*)d_in[1];
    float* out = (float*)d_out;

    const int R = in_sizes[0] / 128;          // 131072
    const int waves_per_block = 256 / 64;     // 4 rays per block
    const int grid = (R + waves_per_block - 1) / waves_per_block;

    vr_kernel<<<grid, 256, 0, stream>>>(alpha, rgbs, out, R);
}